// Round 4
// baseline (305.960 us; speedup 1.0000x reference)
//
#include <hip/hip_runtime.h>
#include <stdint.h>

#define HH 1024
#define WW 2048
#define HWC (HH * WW)
#define NC 19
#define RAD 16
#define TR 32
#define TC 128
#define IC 160          // TC + 2*RAD input columns
#define SN 165          // LDS row stride (dwords): bank=(5*row+16*seg+k)%32 -> 2-way = free
#define TABN 1090       // n*ln(n) table, n in [0, 33*33]
static constexpr float INV_LN19 = 1.0f / 2.9444389791664403f;

static __device__ __forceinline__ int imin(int a, int b) { return a < b ? a : b; }
static __device__ __forceinline__ int imax(int a, int b) { return a > b ? a : b; }

// ---------------- K1: softmax entropy + argmax, 4 pixels/thread ----------------
__global__ __launch_bounds__(256) void k1_pix(const float* __restrict__ logit,
                                              const float* __restrict__ cw,
                                              uint8_t* __restrict__ predict,
                                              float* __restrict__ wtent) {
    int t = blockIdx.x * 256 + threadIdx.x;   // 524288 threads
    int p0 = t * 4;
    float xx[4][NC];
#pragma unroll
    for (int c = 0; c < NC; ++c) {
        float4 v = *reinterpret_cast<const float4*>(logit + (size_t)c * HWC + p0);
        xx[0][c] = v.x; xx[1][c] = v.y; xx[2][c] = v.z; xx[3][c] = v.w;
    }
    float went[4];
    int ids[4];
#pragma unroll
    for (int e = 0; e < 4; ++e) {
        float m = xx[e][0]; int id = 0;
#pragma unroll
        for (int c = 1; c < NC; ++c) { if (xx[e][c] > m) { m = xx[e][c]; id = c; } }
        float s = 0.f, u = 0.f;
#pragma unroll
        for (int c = 0; c < NC; ++c) {
            float d = xx[e][c] - m;
            float ex = __expf(d);
            s += ex;
            u = fmaf(ex, d, u);
        }
        float ent = __logf(s) - u / s;        // == -sum p*log p  (1e-6 bias ~2e-5, negligible)
        went[e] = ent * cw[id] * INV_LN19;
        ids[e] = id;
    }
    uint32_t packed = (uint32_t)ids[0] | ((uint32_t)ids[1] << 8) |
                      ((uint32_t)ids[2] << 16) | ((uint32_t)ids[3] << 24);
    *reinterpret_cast<uint32_t*>(predict + p0) = packed;
    *reinterpret_cast<float4*>(wtent + p0) = make_float4(went[0], went[1], went[2], went[3]);
}

// ---------------- K23: fused 33x33 box passes; table-based impurity ----------------------
// Tile: 32 output rows x 128 output cols. Vertical threads (tid<160) own one input column.
// 5 passes x 4 packed classes (u8x4 vertical counts; u16-pair horizontal slide).
// Impurity via integer identity:  imp = INV_LN19 * ( lnN - (1/N) * sum_c n_c*ln(n_c) )
// with sum_c n_c == N == nh*nw exactly, and n_c*ln(n_c) from a 1090-entry LDS table
// (replaces 320 __logf/thread with LDS gathers; bias from dropping the +1e-6 is <=2e-5).
__global__ __launch_bounds__(256) void k23_fused(const uint8_t* __restrict__ predict,
                                                 const float* __restrict__ wtent,
                                                 float* __restrict__ out) {
    __shared__ uint32_t s_cnt[TR * SN];   // 21120 B: packed vertical counts; later rim plane
    __shared__ float    s_ce[TR * SN];    // 21120 B: vertical entropy sums; later unc plane
    __shared__ float    s_tab[TABN];      //  4360 B: n*ln(n)
    const uint32_t M = 0x00FF00FFu;

    int tid = threadIdx.x;
    int r0 = blockIdx.y * TR;
    int w0 = blockIdx.x * TC;

    // ---- build n*ln(n) table (fenced by the first pass's __syncthreads) ----
    for (int k = tid; k < TABN; k += 256)
        s_tab[k] = (k == 0) ? 0.f : (float)k * __logf((float)k);

    // ---- vertical prep (tid<160): predict column -> 16 packed regs; entropy slide -> s_ce
    uint32_t colreg[16];
    int w = w0 - RAD + tid;
    bool wok = (tid < IC) && ((unsigned)w < WW);
    int wcl = wok ? w : 0;
    if (tid < IC) {
#pragma unroll
        for (int g = 0; g < 16; ++g) {
            uint32_t acc = 0;
#pragma unroll
            for (int b = 0; b < 4; ++b) {
                int grow = r0 - RAD + 4 * g + b;
                bool rok = (unsigned)grow < HH;
                uint32_t pin = (uint32_t)predict[(size_t)(rok ? grow : 0) * WW + wcl];
                if (!(rok && wok)) pin = 255u;
                acc |= pin << (8 * b);
            }
            colreg[g] = acc;
        }
        const float* wp = wtent + wcl;
        float es = 0.f;
#pragma unroll
        for (int h = 0; h < 32; ++h) {
            int grow = r0 - RAD + h;
            if (wok && (unsigned)grow < HH) es += wp[(size_t)grow * WW];
        }
#pragma unroll
        for (int rr = 0; rr < 32; ++rr) {
            int ga = r0 + RAD + rr;
            if (wok && (unsigned)ga < HH) es += wp[(size_t)ga * WW];
            s_ce[rr * SN + tid] = es;
            int gs = r0 - RAD + rr;
            if (wok && (unsigned)gs < HH) es -= wp[(size_t)gs * WW];
        }
    }

    // ---- per-thread output geometry: row = tid&31 (conflict-free LDS), seg = tid>>5
    int row = tid & 31;
    int seg = tid >> 5;
    int c0 = seg * 16;
    int r = r0 + row;
    float nh = (float)(imin(r + RAD, HH - 1) - imax(r - RAD, 0) + 1);
    float rcpN[16], imp[16];
#pragma unroll
    for (int j = 0; j < 16; ++j) {
        int wc = w0 + c0 + j;
        float nw = (float)(imin(wc + RAD, WW - 1) - imax(wc - RAD, 0) + 1);
        rcpN[j] = 1.0f / (nh * nw);
        imp[j] = 0.f;                        // accumulates sum_c n_c*ln(n_c)
    }

    // ---- 5 passes x 4 classes ----
    for (int p = 0; p < 5; ++p) {
        __syncthreads();                      // prev pass's reads done before overwriting s_cnt
        if (tid < IC) {
            uint32_t m[32];
            uint32_t cnt = 0;
#pragma unroll
            for (int h = 0; h < 32; ++h) {
                uint32_t pin = (colreg[h >> 2] >> ((h & 3) * 8)) & 255u;
                uint32_t mm = ((int)(pin >> 2) == p) ? (1u << ((pin & 3u) << 3)) : 0u;
                m[h] = mm;
                cnt += mm;
            }
#pragma unroll
            for (int rr = 0; rr < 32; ++rr) {
                int h = rr + 32;
                uint32_t pin = (colreg[h >> 2] >> ((h & 3) * 8)) & 255u;
                uint32_t mm = ((int)(pin >> 2) == p) ? (1u << ((pin & 3u) << 3)) : 0u;
                cnt += mm;
                s_cnt[rr * SN + tid] = cnt;   // packed u8x4 vertical counts (<=33 each)
                cnt -= m[rr];
            }
        }
        __syncthreads();
        const uint32_t* base = s_cnt + row * SN + c0;
        uint32_t cache[16];
        uint32_t lo = 0, hi = 0;              // u16-pairs: lo={b0,b2}, hi={b1,b3}
#pragma unroll
        for (int k = 0; k < 32; ++k) {
            uint32_t v = base[k];
            if (k < 16) cache[k] = v;
            lo += v & M;
            hi += (v >> 8) & M;
        }
#pragma unroll
        for (int j = 0; j < 16; ++j) {
            uint32_t vin = base[j + 32];
            uint32_t nlo = lo + (vin & M);
            uint32_t nhi = hi + ((vin >> 8) & M);
            imp[j] += s_tab[nlo & 0xFFFFu] + s_tab[nhi & 0xFFFFu] +
                      s_tab[nlo >> 16]     + s_tab[nhi >> 16];
            uint32_t vo = cache[j];
            lo = nlo - (vo & M);
            hi = nhi - ((vo >> 8) & M);
        }
    }

    // ---- horizontal entropy slide (s_ce untouched during passes) ----
    const float* ep = s_ce + row * SN + c0;
    float ecache[16];
    float erun = 0.f;
#pragma unroll
    for (int k = 0; k < 32; ++k) {
        float v = ep[k];
        if (k < 16) ecache[k] = v;
        erun += v;
    }
    float unc[16];
#pragma unroll
    for (int j = 0; j < 16; ++j) {
        float esum = erun + ep[j + 32];
        unc[j] = esum * rcpN[j];
        erun = esum - ecache[j];
    }
    __syncthreads();                          // all s_ce reads complete before overwrite

    // ---- stage result planes in LDS, then fully-coalesced stores ----
    float* rimp = reinterpret_cast<float*>(s_cnt);
#pragma unroll
    for (int j = 0; j < 16; ++j) {
        // rim = INV_LN19 * (lnN - A*rcpN),  lnN = -ln(rcpN)
        rimp[row * SN + c0 + j] = INV_LN19 * (-__logf(rcpN[j]) - imp[j] * rcpN[j]);
        s_ce[row * SN + c0 + j] = unc[j];
    }
    __syncthreads();
#pragma unroll
    for (int i = 0; i < 16; ++i) {
        int idx = tid + 256 * i;              // 0..4095 over 32x128 tile
        int rr = idx >> 7, cc = idx & 127;
        float rim = rimp[rr * SN + cc];
        float un = s_ce[rr * SN + cc];
        size_t o = (size_t)(r0 + rr) * WW + (w0 + cc);
        out[o] = rim * un;                    // score
        out[HWC + o] = rim;                   // region_impurity
        out[2 * HWC + o] = un;                // prediction_uncertainty
    }
}

extern "C" void kernel_launch(void* const* d_in, const int* in_sizes, int n_in,
                              void* d_out, int out_size, void* d_ws, size_t ws_size,
                              hipStream_t stream) {
    const float* logit = (const float*)d_in[0];
    const float* cw = (const float*)d_in[1];
    float* out = (float*)d_out;
    uint8_t* ws = (uint8_t*)d_ws;

    uint8_t* predict = ws;                              // 2 MB  u8 [1024][2048]
    float* wtent = (float*)(ws + 2097152);              // 8 MB  f32 [1024][2048]

    k1_pix<<<2048, 256, 0, stream>>>(logit, cw, predict, wtent);
    k23_fused<<<dim3(WW / TC, HH / TR), 256, 0, stream>>>(predict, wtent, out);
}

// Round 5
// 283.733 us; speedup vs baseline: 1.0783x; 1.0783x over previous
//
#include <hip/hip_runtime.h>
#include <hip/hip_fp16.h>
#include <stdint.h>

#define HH 1024
#define WW 2048
#define HWC (HH * WW)
#define NC 19
#define RAD 16
#define TR 32
#define TC 128
#define IC 160          // TC + 2*RAD input columns
#define SN 165          // LDS row stride (dwords): bank=(5*row+16*seg+k)%32 -> 2-way = free
static constexpr float INV_LN19 = 1.0f / 2.9444389791664403f;

static __device__ __forceinline__ int imin(int a, int b) { return a < b ? a : b; }
static __device__ __forceinline__ int imax(int a, int b) { return a > b ? a : b; }

// ---------------- K1: softmax entropy + argmax, 4 pixels/thread ----------------
__global__ __launch_bounds__(256) void k1_pix(const float* __restrict__ logit,
                                              const float* __restrict__ cw,
                                              uint8_t* __restrict__ predict,
                                              uint16_t* __restrict__ wtent) {
    int t = blockIdx.x * 256 + threadIdx.x;   // 524288 threads
    int p0 = t * 4;
    float xx[4][NC];
#pragma unroll
    for (int c = 0; c < NC; ++c) {
        float4 v = *reinterpret_cast<const float4*>(logit + (size_t)c * HWC + p0);
        xx[0][c] = v.x; xx[1][c] = v.y; xx[2][c] = v.z; xx[3][c] = v.w;
    }
    float went[4];
    int ids[4];
#pragma unroll
    for (int e = 0; e < 4; ++e) {
        float m = xx[e][0]; int id = 0;
#pragma unroll
        for (int c = 1; c < NC; ++c) { if (xx[e][c] > m) { m = xx[e][c]; id = c; } }
        float s = 0.f, u = 0.f;
#pragma unroll
        for (int c = 0; c < NC; ++c) {
            float d = xx[e][c] - m;
            float ex = __expf(d);
            s += ex;
            u = fmaf(ex, d, u);
        }
        float ent = __logf(s) - u / s;        // == -sum p*log p  (1e-6 bias ~2e-5, negligible)
        went[e] = ent * cw[id] * INV_LN19;
        ids[e] = id;
    }
    uint32_t packed = (uint32_t)ids[0] | ((uint32_t)ids[1] << 8) |
                      ((uint32_t)ids[2] << 16) | ((uint32_t)ids[3] << 24);
    *reinterpret_cast<uint32_t*>(predict + p0) = packed;
    // wtent as fp16 (halves HBM traffic; <=4.9e-4 rel err, averaged down by the 1089-tap box)
    __half h0 = __float2half_rn(went[0]), h1 = __float2half_rn(went[1]);
    __half h2 = __float2half_rn(went[2]), h3 = __float2half_rn(went[3]);
    uint2 pk;
    pk.x = (uint32_t)__half_as_ushort(h0) | ((uint32_t)__half_as_ushort(h1) << 16);
    pk.y = (uint32_t)__half_as_ushort(h2) | ((uint32_t)__half_as_ushort(h3) << 16);
    *reinterpret_cast<uint2*>(wtent + p0) = pk;
}

// ---------------- K23: fused 33x33 box passes; 4-class packed; conflict-free LDS ----------
// (round-3 structure — the measured-best config; table variant reverted: dependent LDS
//  gathers put ~120-cyc latency on the slide chain, -20us regression)
__global__ __launch_bounds__(256) void k23_fused(const uint8_t* __restrict__ predict,
                                                 const uint16_t* __restrict__ wtent,
                                                 float* __restrict__ out) {
    __shared__ uint32_t s_cnt[TR * SN];   // 21120 B: packed vertical counts; later rim plane
    __shared__ float    s_ce[TR * SN];    // 21120 B: vertical entropy sums; later unc plane
    const uint32_t M = 0x00FF00FFu;

    int tid = threadIdx.x;
    int r0 = blockIdx.y * TR;
    int w0 = blockIdx.x * TC;

    // ---- vertical prep (tid<160): predict column -> 16 packed regs; entropy slide -> s_ce
    uint32_t colreg[16];
    int w = w0 - RAD + tid;
    bool wok = (tid < IC) && ((unsigned)w < WW);
    int wcl = wok ? w : 0;
    if (tid < IC) {
#pragma unroll
        for (int g = 0; g < 16; ++g) {
            uint32_t acc = 0;
#pragma unroll
            for (int b = 0; b < 4; ++b) {
                int grow = r0 - RAD + 4 * g + b;
                bool rok = (unsigned)grow < HH;
                uint32_t pin = (uint32_t)predict[(size_t)(rok ? grow : 0) * WW + wcl];
                if (!(rok && wok)) pin = 255u;
                acc |= pin << (8 * b);
            }
            colreg[g] = acc;
        }
        const uint16_t* wp = wtent + wcl;
        float es = 0.f;
#pragma unroll
        for (int h = 0; h < 32; ++h) {
            int grow = r0 - RAD + h;
            if (wok && (unsigned)grow < HH)
                es += __half2float(__ushort_as_half(wp[(size_t)grow * WW]));
        }
#pragma unroll
        for (int rr = 0; rr < 32; ++rr) {
            int ga = r0 + RAD + rr;
            if (wok && (unsigned)ga < HH)
                es += __half2float(__ushort_as_half(wp[(size_t)ga * WW]));
            s_ce[rr * SN + tid] = es;
            int gs = r0 - RAD + rr;
            if (wok && (unsigned)gs < HH)
                es -= __half2float(__ushort_as_half(wp[(size_t)gs * WW]));
        }
    }

    // ---- per-thread output geometry: row = tid&31 (conflict-free LDS), seg = tid>>5
    int row = tid & 31;
    int seg = tid >> 5;
    int c0 = seg * 16;
    int r = r0 + row;
    float nh = (float)(imin(r + RAD, HH - 1) - imax(r - RAD, 0) + 1);
    float rcpN[16], imp[16];
#pragma unroll
    for (int j = 0; j < 16; ++j) {
        int wc = w0 + c0 + j;
        float nw = (float)(imin(wc + RAD, WW - 1) - imax(wc - RAD, 0) + 1);
        rcpN[j] = 1.0f / (nh * nw);
        imp[j] = 0.f;
    }

    // ---- 5 passes x 4 classes ----
    for (int p = 0; p < 5; ++p) {
        __syncthreads();                      // prev pass's reads done before overwriting s_cnt
        if (tid < IC) {
            uint32_t m[32];
            uint32_t cnt = 0;
#pragma unroll
            for (int h = 0; h < 32; ++h) {
                uint32_t pin = (colreg[h >> 2] >> ((h & 3) * 8)) & 255u;
                uint32_t mm = ((int)(pin >> 2) == p) ? (1u << ((pin & 3u) << 3)) : 0u;
                m[h] = mm;
                cnt += mm;
            }
#pragma unroll
            for (int rr = 0; rr < 32; ++rr) {
                int h = rr + 32;
                uint32_t pin = (colreg[h >> 2] >> ((h & 3) * 8)) & 255u;
                uint32_t mm = ((int)(pin >> 2) == p) ? (1u << ((pin & 3u) << 3)) : 0u;
                cnt += mm;
                s_cnt[rr * SN + tid] = cnt;   // packed u8x4 vertical counts (<=33 each)
                cnt -= m[rr];
            }
        }
        __syncthreads();
        const uint32_t* base = s_cnt + row * SN + c0;
        uint32_t cache[16];
        uint32_t lo = 0, hi = 0;              // u16-pairs: lo={b0,b2}, hi={b1,b3}
#pragma unroll
        for (int k = 0; k < 32; ++k) {
            uint32_t v = base[k];
            if (k < 16) cache[k] = v;
            lo += v & M;
            hi += (v >> 8) & M;
        }
#pragma unroll
        for (int j = 0; j < 16; ++j) {
            uint32_t vin = base[j + 32];
            uint32_t nlo = lo + (vin & M);
            uint32_t nhi = hi + ((vin >> 8) & M);
            float n0 = (float)(nlo & 0xFFFFu);
            float n1 = (float)(nhi & 0xFFFFu);
            float n2 = (float)(nlo >> 16);
            float n3 = (float)(nhi >> 16);
            float d0 = n0 * rcpN[j], d1 = n1 * rcpN[j];
            float d2 = n2 * rcpN[j], d3 = n3 * rcpN[j];
            imp[j] = fmaf(d0, __logf(d0 + 1e-6f), imp[j]);
            imp[j] = fmaf(d1, __logf(d1 + 1e-6f), imp[j]);
            imp[j] = fmaf(d2, __logf(d2 + 1e-6f), imp[j]);
            imp[j] = fmaf(d3, __logf(d3 + 1e-6f), imp[j]);
            uint32_t vo = cache[j];
            lo = nlo - (vo & M);
            hi = nhi - ((vo >> 8) & M);
        }
    }

    // ---- horizontal entropy slide (s_ce untouched during passes) ----
    const float* ep = s_ce + row * SN + c0;
    float ecache[16];
    float erun = 0.f;
#pragma unroll
    for (int k = 0; k < 32; ++k) {
        float v = ep[k];
        if (k < 16) ecache[k] = v;
        erun += v;
    }
    float unc[16];
#pragma unroll
    for (int j = 0; j < 16; ++j) {
        float esum = erun + ep[j + 32];
        unc[j] = esum * rcpN[j];
        erun = esum - ecache[j];
    }
    __syncthreads();                          // all s_ce reads complete before overwrite

    // ---- stage result planes in LDS, then fully-coalesced stores ----
    float* rimp = reinterpret_cast<float*>(s_cnt);
#pragma unroll
    for (int j = 0; j < 16; ++j) {
        rimp[row * SN + c0 + j] = imp[j] * (-INV_LN19);
        s_ce[row * SN + c0 + j] = unc[j];
    }
    __syncthreads();
#pragma unroll
    for (int i = 0; i < 16; ++i) {
        int idx = tid + 256 * i;              // 0..4095 over 32x128 tile
        int rr = idx >> 7, cc = idx & 127;
        float rim = rimp[rr * SN + cc];
        float un = s_ce[rr * SN + cc];
        size_t o = (size_t)(r0 + rr) * WW + (w0 + cc);
        out[o] = rim * un;                    // score
        out[HWC + o] = rim;                   // region_impurity
        out[2 * HWC + o] = un;                // prediction_uncertainty
    }
}

extern "C" void kernel_launch(void* const* d_in, const int* in_sizes, int n_in,
                              void* d_out, int out_size, void* d_ws, size_t ws_size,
                              hipStream_t stream) {
    const float* logit = (const float*)d_in[0];
    const float* cw = (const float*)d_in[1];
    float* out = (float*)d_out;
    uint8_t* ws = (uint8_t*)d_ws;

    uint8_t* predict = ws;                              // 2 MB  u8  [1024][2048]
    uint16_t* wtent = (uint16_t*)(ws + 2097152);        // 4 MB  f16 [1024][2048]

    k1_pix<<<2048, 256, 0, stream>>>(logit, cw, predict, wtent);
    k23_fused<<<dim3(WW / TC, HH / TR), 256, 0, stream>>>(predict, wtent, out);
}